// Round 1
// baseline (332.801 us; speedup 1.0000x reference)
//
#include <hip/hip_runtime.h>

// ---------------------------------------------------------------------------
// SeqPairAttentionOutput on MI355X — round 6: 7 launches.
// r6: gemm64 -> depth-3 pipelined staging over 4 LDS buffers with counted
// s_waitcnt vmcnt(4/2/0) + raw s_barrier (no full vmcnt drain per iter).
// Everything else unchanged from r5.
// ---------------------------------------------------------------------------

typedef __attribute__((ext_vector_type(8))) short bfrag;   // 8 bf16 (4 VGPRs)
typedef __attribute__((ext_vector_type(4))) float f32x4;
typedef unsigned short ushort_t;
typedef unsigned int u32;

#define AS1 __attribute__((address_space(1)))
#define AS3 __attribute__((address_space(3)))

__device__ __forceinline__ void gll16(const void* g, void* l) {
  __builtin_amdgcn_global_load_lds((const AS1 u32*)g, (AS3 u32*)l, 16, 0, 0);
}

__device__ __forceinline__ unsigned short f2b(float x) {
  union { float f; unsigned u; } a; a.f = x;
  unsigned r = a.u + 0x7fffu + ((a.u >> 16) & 1u);   // RNE
  return (unsigned short)(r >> 16);
}
__device__ __forceinline__ unsigned pack2(float a, float b) {
  return (unsigned)f2b(a) | ((unsigned)f2b(b) << 16);
}
__device__ __forceinline__ float b2f(ushort_t u) {
  union { float f; unsigned v; } a; a.v = ((unsigned)u) << 16; return a.f;
}

// workspace layout (bytes)
#define OFF_BIASH ((size_t)0)                        // bias bf16 [16][512][512] 8MB
#define OFF_Y     ((size_t)8388608)                  // y bf16 [512][1024] 1MB
#define OFF_QS    (OFF_Y    + (size_t)1048576)
#define OFF_KS    (OFF_QS   + (size_t)1048576)
#define OFF_VT    (OFF_KS   + (size_t)1048576)       // v^T bf16 [16][64][512]
#define OFF_GATE  (OFF_VT   + (size_t)1048576)       // gate f32 [512][1024] 2MB
#define OFF_OG    (OFF_GATE + (size_t)2097152)       // gate*o bf16 1MB
#define OFF_S     (OFF_OG   + (size_t)1048576)       // s f32 2MB
#define OFF_HLN   (OFF_S    + (size_t)2097152)       // LN(s) bf16 1MB
#define OFF_H1    (OFF_HLN  + (size_t)1048576)       // h1 bf16 [512][4096] 4MB
#define OFF_WPG   (OFF_H1   + (size_t)4194304)       // [proj|g]^T bf16 [4096][1024] 8MB
#define OFF_WO    (OFF_WPG  + (size_t)8388608)       // o_w^T bf16 2MB
#define OFF_W1    (OFF_WO   + (size_t)2097152)       // w1^T bf16 8MB
#define OFF_W2    (OFF_W1   + (size_t)8388608)       // w2^T bf16 8MB

// ---------------------------------------------------------------------------
// transpose + cvt helper: W[K][N] -> Wt[N][K] bf16 (one 64x64 tile)
// ---------------------------------------------------------------------------
__device__ __forceinline__ void transp_tile(
    const float* __restrict__ W, ushort_t* __restrict__ Wt, int K, int N,
    int bx, int by, int tid, float* smem) {
  float (*tile)[65] = (float(*)[65])smem;
  int n0 = bx * 64, k0 = by * 64;
  int tr = tid >> 4, tc = (tid & 15) * 4;
#pragma unroll
  for (int i = 0; i < 4; i++) {
    int r = tr + i * 16;
    f32x4 v = __builtin_nontemporal_load(
        (const f32x4*)&W[(long)(k0 + r) * N + n0 + tc]);
    tile[r][tc] = v.x; tile[r][tc + 1] = v.y; tile[r][tc + 2] = v.z; tile[r][tc + 3] = v.w;
  }
  __syncthreads();
  int nr = tid >> 2, kk = (tid & 3) * 16;
  ushort_t* dst = Wt + (long)(n0 + nr) * K + k0 + kk;
  uint4 q;
  q.x = pack2(tile[kk + 0][nr], tile[kk + 1][nr]);
  q.y = pack2(tile[kk + 2][nr], tile[kk + 3][nr]);
  q.z = pack2(tile[kk + 4][nr], tile[kk + 5][nr]);
  q.w = pack2(tile[kk + 6][nr], tile[kk + 7][nr]);
  *(uint4*)dst = q;
  uint4 q2;
  q2.x = pack2(tile[kk + 8][nr],  tile[kk + 9][nr]);
  q2.y = pack2(tile[kk + 10][nr], tile[kk + 11][nr]);
  q2.z = pack2(tile[kk + 12][nr], tile[kk + 13][nr]);
  q2.w = pack2(tile[kk + 14][nr], tile[kk + 15][nr]);
  *(uint4*)(dst + 8) = q2;
}

// ---------------------------------------------------------------------------
// mega1: [0,4096) p2s MFMA | [4096,7424) transposes | [7424,7936) ln1+sbuf
// ---------------------------------------------------------------------------
__global__ __launch_bounds__(256) void mega1(
    const float* __restrict__ pw,
    const float* __restrict__ p2s_g, const float* __restrict__ p2s_b,
    const float* __restrict__ p2s_w,
    const float* __restrict__ proj_w, const float* __restrict__ g_w,
    const float* __restrict__ o_w, const float* __restrict__ w1,
    const float* __restrict__ w2,
    const float* __restrict__ seq, const float* __restrict__ ln1_g,
    const float* __restrict__ ln1_b, const float* __restrict__ o_b,
    ushort_t* __restrict__ biasH, ushort_t* __restrict__ wpg,
    ushort_t* __restrict__ wo, ushort_t* __restrict__ w1t,
    ushort_t* __restrict__ w2t, ushort_t* __restrict__ ybf,
    float* __restrict__ sbuf) {
  __shared__ float smemF[5920];
  const int id = blockIdx.x, t = threadIdx.x;

  if (id < 4096) {
    // ---- p2s: 64 pairs/block, MFMA dot ----
    ushort_t* wb  = (ushort_t*)smemF;        // 2048
    ushort_t* zsb = wb + 2048;               // 64 x 136
    ushort_t* res = zsb + 64 * 136;          // 16 x 68
    const int w = t >> 6, lane = t & 63, ln = lane & 15, quad = lane >> 4;
    const long pair0 = (long)id * 64;
    const int p = w * 16 + (lane >> 2);      // local pair 0..63
    const int j = lane & 3;                  // quarter

    // stage w coalesced -> bf16 B-frag layout
#pragma unroll
    for (int i = t; i < 2048; i += 256) {
      int f = i >> 4, hh = i & 15;
      int chunk = f >> 5, q2 = (f >> 3) & 3, jj = f & 7;
      wb[(chunk * 64 + q2 * 16 + hh) * 8 + jj] = f2b(p2s_w[i]);
    }

    // x comb loads: lane j reads floats {j*4 + q*16 .. +4}, 64B line per 4 lanes
    const float* xbase = pw + (pair0 + p) * 128 + j * 4;
    f32x4 xv[8];
#pragma unroll
    for (int q = 0; q < 8; q++)
      xv[q] = __builtin_nontemporal_load((const f32x4*)(xbase + q * 16));
    float s = 0.f, sq = 0.f;
#pragma unroll
    for (int q = 0; q < 8; q++) {
      s  += xv[q].x + xv[q].y + xv[q].z + xv[q].w;
      sq += xv[q].x*xv[q].x + xv[q].y*xv[q].y + xv[q].z*xv[q].z + xv[q].w*xv[q].w;
    }
    s += __shfl_xor(s, 1); s += __shfl_xor(s, 2);
    sq += __shfl_xor(sq, 1); sq += __shfl_xor(sq, 2);
    float mu = s * (1.f / 128.f);
    float rs = rsqrtf(sq * (1.f / 128.f) - mu * mu + 1e-5f);

#pragma unroll
    for (int q = 0; q < 8; q++) {
      f32x4 gv = *(const f32x4*)(p2s_g + j * 4 + q * 16);
      f32x4 bv = *(const f32x4*)(p2s_b + j * 4 + q * 16);
      uint2 o;
      o.x = pack2((xv[q].x - mu) * rs * gv.x + bv.x, (xv[q].y - mu) * rs * gv.y + bv.y);
      o.y = pack2((xv[q].z - mu) * rs * gv.z + bv.z, (xv[q].w - mu) * rs * gv.w + bv.w);
      *(uint2*)&zsb[p * 136 + q * 16 + j * 4] = o;
    }
    __syncthreads();

    // wave w: pairs [w*16, w*16+16) x 16 heads, K=128 via 4 MFMA
    f32x4 acc = (f32x4){0.f, 0.f, 0.f, 0.f};
#pragma unroll
    for (int chunk = 0; chunk < 4; chunk++) {
      bfrag a  = *(const bfrag*)&zsb[(w * 16 + ln) * 136 + chunk * 32 + quad * 8];
      bfrag bf = *(const bfrag*)&wb[(chunk * 64 + quad * 16 + ln) * 8];
      acc = __builtin_amdgcn_mfma_f32_16x16x32_bf16(a, bf, acc, 0, 0, 0);
    }
    *(uint2*)&res[ln * 68 + w * 16 + quad * 4] =
        (uint2){pack2(acc[0], acc[1]), pack2(acc[2], acc[3])};
    __syncthreads();
    {
      int hh = t >> 4, base = (t & 15) * 4;
      *(uint2*)&biasH[(long)hh * 262144 + pair0 + base] =
          *(const uint2*)&res[hh * 68 + base];
    }
  } else if (id < 7424) {
    int j = id - 4096;
    if (j < 768)       transp_tile(proj_w, wpg, 1024, 3072, j % 48, j / 48, t, smemF);
    else if (j < 1024) { j -= 768;  transp_tile(g_w, wpg + (long)3072 * 1024, 1024, 1024, j % 16, j / 16, t, smemF); }
    else if (j < 1280) { j -= 1024; transp_tile(o_w, wo, 1024, 1024, j % 16, j / 16, t, smemF); }
    else if (j < 2304) { j -= 1280; transp_tile(w1, w1t, 1024, 4096, j % 64, j / 64, t, smemF); }
    else               { j -= 2304; transp_tile(w2, w2t, 4096, 1024, j % 16, j / 16, t, smemF); }
  } else {
    // ---- ln1 + sbuf init ----
    int row = id - 7424;
    long base = (long)row * 1024 + t * 4;
    float4 v = *(const float4*)(seq + base);
    float4 ob = *(const float4*)(o_b + t * 4);
    float4 sv; sv.x = v.x + ob.x; sv.y = v.y + ob.y; sv.z = v.z + ob.z; sv.w = v.w + ob.w;
    *(float4*)(sbuf + base) = sv;
    float s  = v.x + v.y + v.z + v.w;
    float sq = v.x*v.x + v.y*v.y + v.z*v.z + v.w*v.w;
#pragma unroll
    for (int k = 1; k < 64; k <<= 1) { s += __shfl_xor(s, k); sq += __shfl_xor(sq, k); }
    if ((t & 63) == 0) { smemF[t >> 6] = s; smemF[4 + (t >> 6)] = sq; }
    __syncthreads();
    s  = smemF[0] + smemF[1] + smemF[2] + smemF[3];
    sq = smemF[4] + smemF[5] + smemF[6] + smemF[7];
    float mu = s * (1.f / 1024.f);
    float rsd = rsqrtf(sq * (1.f / 1024.f) - mu * mu + 1e-5f);
    float4 gv = *(const float4*)(ln1_g + t * 4);
    float4 bv = *(const float4*)(ln1_b + t * 4);
    uint2 o;
    o.x = pack2((v.x - mu) * rsd * gv.x + bv.x, (v.y - mu) * rsd * gv.y + bv.y);
    o.y = pack2((v.z - mu) * rsd * gv.z + bv.z, (v.w - mu) * rsd * gv.w + bv.w);
    *(uint2*)(ybf + base) = o;
  }
}

// ---------------------------------------------------------------------------
// gemm64: 64x64 tile, depth-3 pipelined gll16 staging over 4 LDS buffers,
// counted s_waitcnt vmcnt (never a full drain in steady state), one raw
// s_barrier per K-iter. 4 waves 2x2, each 32x32 (4 MFMA / K-32).
// Hazards: with 4 bufs, tile k+3 overwrites the buf last read at iter k-1;
// every wave is past that read at iter-k's barrier -> one barrier suffices.
// vmcnt: 2 gll16/wave/tile -> steady outstanding 6, wait to 4 (tile k done).
// sched_barrier(0) after s_barrier pins ds_read/gll16 from hoisting between
// the counted wait and the barrier (cross-wave staging visibility).
// EPI 3: relu(acc+bias1)->bf16 | EPI 6: qkv/gate scatter | EPI 7: atomicAdd f32
// ---------------------------------------------------------------------------
template <int EPI>
__global__ __launch_bounds__(256) void gemm64(
    const ushort_t* __restrict__ A, const ushort_t* __restrict__ Bt,
    int lda, int ldb, int Ksplit,
    const float* __restrict__ bias1,
    float* __restrict__ outF, ushort_t* __restrict__ outH, int ldc,
    ushort_t* __restrict__ qs, ushort_t* __restrict__ ks,
    ushort_t* __restrict__ vt, float* __restrict__ gatebuf) {
  __shared__ ushort_t As[4][64 * 32];   // 4 KB each
  __shared__ ushort_t Bs[4][64 * 32];
  const int tid = threadIdx.x;
  const int w = tid >> 6, lane = tid & 63;
  const int ln = lane & 15, quad = lane >> 4;
  const int wm = w >> 1, wn = w & 1;
  const int m0 = blockIdx.y * 64, n0 = blockIdx.x * 64;
  const int z = blockIdx.z;
  const int Koff = (EPI == 7) ? z * Ksplit : 0;

  const ushort_t* ga = A  + (long)(m0 + (tid >> 2)) * lda + Koff + (tid & 3) * 8;
  const ushort_t* gb = Bt + (long)(n0 + (tid >> 2)) * ldb + Koff + (tid & 3) * 8;
  unsigned wofs = __builtin_amdgcn_readfirstlane(w * 1024);
  char* lAw = (char*)&As[0][0] + wofs;
  char* lBw = (char*)&Bs[0][0] + wofs;

  f32x4 acc[2][2];
#pragma unroll
  for (int i = 0; i < 2; i++)
#pragma unroll
    for (int jj = 0; jj < 2; jj++) acc[i][jj] = (f32x4){0.f, 0.f, 0.f, 0.f};

  auto stage = [&](int t) {
    int boff = (t & 3) * 4096;
    gll16(ga + t * 32, lAw + boff);
    gll16(gb + t * 32, lBw + boff);
  };
  auto body = [&](int b) {
    const ushort_t* Ab = (const ushort_t*)((const char*)&As[0][0] + b * 4096);
    const ushort_t* Bb = (const ushort_t*)((const char*)&Bs[0][0] + b * 4096);
    bfrag a0 = *(const bfrag*)&Ab[(wm * 32 + ln) * 32 + quad * 8];
    bfrag a1 = *(const bfrag*)&Ab[(wm * 32 + 16 + ln) * 32 + quad * 8];
    bfrag b0 = *(const bfrag*)&Bb[(wn * 32 + ln) * 32 + quad * 8];
    bfrag b1 = *(const bfrag*)&Bb[(wn * 32 + 16 + ln) * 32 + quad * 8];
    acc[0][0] = __builtin_amdgcn_mfma_f32_16x16x32_bf16(a0, b0, acc[0][0], 0, 0, 0);
    acc[0][1] = __builtin_amdgcn_mfma_f32_16x16x32_bf16(a0, b1, acc[0][1], 0, 0, 0);
    acc[1][0] = __builtin_amdgcn_mfma_f32_16x16x32_bf16(a1, b0, acc[1][0], 0, 0, 0);
    acc[1][1] = __builtin_amdgcn_mfma_f32_16x16x32_bf16(a1, b1, acc[1][1], 0, 0, 0);
  };

  const int niter = Ksplit >> 5;
  stage(0);
  if (niter > 1) stage(1);
  if (niter > 2) stage(2);

  int k = 0;
  for (; k + 2 < niter; ++k) {            // steady state: tiles k+1,k+2 in flight
    asm volatile("s_waitcnt vmcnt(4)" ::: "memory");
    __builtin_amdgcn_s_barrier();
    __builtin_amdgcn_sched_barrier(0);
    if (k + 3 < niter) stage(k + 3);
    body(k & 3);
  }
  for (; k < niter; ++k) {                // tail: drain remaining tiles
    if (k + 1 < niter) { asm volatile("s_waitcnt vmcnt(2)" ::: "memory"); }
    else               { asm volatile("s_waitcnt vmcnt(0)" ::: "memory"); }
    __builtin_amdgcn_s_barrier();
    __builtin_amdgcn_sched_barrier(0);
    body(k & 3);
  }

#pragma unroll
  for (int am = 0; am < 2; am++) {
#pragma unroll
    for (int bn = 0; bn < 2; bn++) {
      int ocol = n0 + wn * 32 + bn * 16 + ln;
#pragma unroll
      for (int r = 0; r < 4; r++) {
        int orow = m0 + wm * 32 + am * 16 + quad * 4 + r;
        float v = acc[am][bn][r];
        if (EPI == 3) {
          v = fmaxf(v + bias1[ocol], 0.f);
          outH[(long)orow * ldc + ocol] = f2b(v);
        } else if (EPI == 6) {
          if (ocol < 3072) {
            int h = ocol / 192, jq = ocol - h * 192;
            if (jq < 64)       qs[((long)h * 512 + orow) * 64 + jq] = f2b(v * 0.125f);
            else if (jq < 128) ks[((long)h * 512 + orow) * 64 + (jq - 64)] = f2b(v);
            else               vt[((long)h * 64 + (jq - 128)) * 512 + orow] = f2b(v);
          } else {
            int gcol = ocol - 3072;
            float gv = v + bias1[gcol];
            gatebuf[(long)orow * 1024 + gcol] = 1.f / (1.f + __expf(-gv));
          }
        } else { // EPI 7
          atomicAdd(&outF[(long)orow * ldc + ocol], v);
        }
      }
    }
  }
}

// ---------------------------------------------------------------------------
// flash attention: block = head x 32 q-rows, 4 waves (wm rows x wn key-half).
// Wave-private online softmax across its 32-key columns; merge once at end.
// 2 barriers/tile. Bias enters as MFMA C operand.
// ---------------------------------------------------------------------------
__global__ __launch_bounds__(256) void flash_attn(
    const ushort_t* __restrict__ qs, const ushort_t* __restrict__ ks,
    const ushort_t* __restrict__ vt, const ushort_t* __restrict__ biasH,
    const float* __restrict__ gate, ushort_t* __restrict__ og) {
  __shared__ ushort_t Qs[32 * 72];
  __shared__ ushort_t Ks[64 * 72];
  __shared__ ushort_t Vs[64 * 72];
  __shared__ ushort_t Ps[4][16 * 40];
  const int tid = threadIdx.x;
  const int w = tid >> 6, lane = tid & 63, ln = lane & 15, quad = lane >> 4;
  const int wm = w >> 1, wn = w & 1;
  const int h = blockIdx.x, q0 = blockIdx.y * 32;

  { int r = tid >> 3, c = (tid & 7) * 8;
    *(uint4*)&Qs[r * 72 + c] = *(const uint4*)(qs + ((long)(h * 512 + q0 + r)) * 64 + c); }

  float m_[4], l_[4];
  f32x4 Oacc[4];
#pragma unroll
  for (int i = 0; i < 4; i++) { m_[i] = -1e30f; l_[i] = 0.f; Oacc[i] = (f32x4){0.f,0.f,0.f,0.f}; }

  const int rkv = tid >> 2, ckv = (tid & 3) * 16;

  for (int kt = 0; kt < 8; kt++) {
    const int k0 = kt * 64;
    __syncthreads();                    // safe to overwrite K/V (covers Qs 1st iter)
    { const ushort_t* sk = ks + ((long)(h * 512 + k0 + rkv)) * 64 + ckv;
      *(uint4*)&Ks[rkv * 72 + ckv]     = *(const uint4*)sk;
      *(uint4*)&Ks[rkv * 72 + ckv + 8] = *(const uint4*)(sk + 8);
      const ushort_t* sv = vt + ((long)(h * 64 + rkv)) * 512 + k0 + ckv;
      *(uint4*)&Vs[rkv * 72 + ckv]     = *(const uint4*)sv;
      *(uint4*)&Vs[rkv * 72 + ckv + 8] = *(const uint4*)(sv + 8); }

    f32x4 acc[2];
    const ushort_t* bp = biasH + ((long)(h * 512 + q0 + wm * 16 + quad * 4)) * 512
                         + k0 + wn * 32 + ln;
#pragma unroll
    for (int t4 = 0; t4 < 2; t4++)
#pragma unroll
      for (int rr = 0; rr < 4; rr++)
        acc[t4][rr] = b2f(bp[(long)rr * 512 + t4 * 16]);

    __syncthreads();                    // K/V ready
#pragma unroll
    for (int s = 0; s < 2; s++) {
      bfrag a = *(const bfrag*)&Qs[(wm * 16 + ln) * 72 + s * 32 + quad * 8];
#pragma unroll
      for (int t4 = 0; t4 < 2; t4++) {
        bfrag b = *(const bfrag*)&Ks[(wn * 32 + t4 * 16 + ln) * 72 + s * 32 + quad * 8];
        acc[t4] = __builtin_amdgcn_mfma_f32_16x16x32_bf16(a, b, acc[t4], 0, 0, 0);
      }
    }

    // wave-private online softmax over this wave's 32 keys
    float mt[4];
#pragma unroll
    for (int rr = 0; rr < 4; rr++) mt[rr] = fmaxf(acc[0][rr], acc[1][rr]);
#pragma unroll
    for (int xm = 1; xm < 16; xm <<= 1)
#pragma unroll
      for (int rr = 0; rr < 4; rr++) mt[rr] = fmaxf(mt[rr], __shfl_xor(mt[rr], xm));
    float al[4];
#pragma unroll
    for (int rr = 0; rr < 4; rr++) {
      float mn = fmaxf(m_[rr], mt[rr]);
      al[rr] = __expf(m_[rr] - mn);
      m_[rr] = mn;
    }
#pragma unroll
    for (int t4 = 0; t4 < 2; t4++)
#pragma unroll
      for (int rr = 0; rr < 4; rr++)
        acc[t4][rr] = __expf(acc[t4][rr] - m_[rr]);
    float rsl[4];
#pragma unroll
    for (int rr = 0; rr < 4; rr++) rsl[rr] = acc[0][rr] + acc[1][rr];
#pragma unroll
    for (int xm = 1; xm < 16; xm <<= 1)
#pragma unroll
      for (int rr = 0; rr < 4; rr++) rsl[rr] += __shfl_xor(rsl[rr], xm);
#pragma unroll
    for (int rr = 0; rr < 4; rr++) l_[rr] = l_[rr] * al[rr] + rsl[rr];
#pragma unroll
    for (int t4 = 0; t4 < 4; t4++)
#pragma unroll
      for (int rr = 0; rr < 4; rr++) Oacc[t4][rr] *= al[rr];

    // P -> wave-private LDS (C-layout -> A-layout round trip)
#pragma unroll
    for (int t4 = 0; t4 < 2; t4++)
#pragma unroll
      for (int rr = 0; rr < 4; rr++)
        Ps[w][(quad * 4 + rr) * 40 + t4 * 16 + ln] = f2b(acc[t4][rr]);
    __builtin_amdgcn_wave_barrier();
    __builtin_amdgcn_s_waitcnt(0xC07F);   // lgkmcnt(0), vm/exp unconstrained
    __builtin_amdgcn_wave_barrier();

    // O += P V (this wave's 32 keys)
    {
      bfrag a = *(const bfrag*)&Ps[w][ln * 40 + quad * 8];
#pragma unroll
      for (int t4 = 0; t4 < 4; t4++) {
        bfrag b = *(const bfrag*)&Vs[(t4 * 16 + ln) * 72 + wn * 32 + quad * 8];
        Oacc[t4] = __builtin_amdgcn_mfma_f32_16x16x32_bf16(a, b, Oacc[t4], 0, 0, 0);
      }
    }
  }

  // merge the two wn key-half streams (flash-decoding style)
  __syncthreads();
  float* ml = (float*)(void*)Ks;    // [4 waves][16 rows][2]
  if (ln == 0)
#pragma unroll
    for (int rr = 0; rr < 4; rr++) {
      ml[(w * 16 + quad * 4 + rr) * 2 + 0] = m_[rr];
      ml[(w * 16 + quad * 4 + rr) * 2 + 1] = l_[rr];
    }
  __syncthreads();
  const int pw_ = wm * 2 + (wn ^ 1);
  float a_self[4];
#pragma unroll
  for (int rr = 0; rr < 4; rr++) {
    float mo = ml[(pw_ * 16 + quad * 4 + rr) * 2 + 0];
    float lo = ml[(pw_ * 16 + quad * 4 + rr) * 2 + 1];
    float mF = fmaxf(m_[rr], mo);
    a_self[rr] = __expf(m_[rr] - mF);
    l_[rr] = l_[rr] * a_self[rr] + lo * __expf(mo - mF);   // final l
  }
  float* Of = (float*)(void*)Vs;    // [2 wm][16 rows][68]
  if (wn == 1) {
#pragma unroll
    for (int t4 = 0; t4 < 4; t4++)
#pragma unroll
      for (int rr = 0; rr < 4; rr++)
        Of[(wm * 16 + quad * 4 + rr) * 68 + t4 * 16 + ln] = Oacc[t4][rr] * a_self[rr];
  }
  __syncthreads();
  if (wn == 0) {
#pragma unroll
    for (int t4 = 0; t4 < 4; t4++) {
#pragma unroll
      for (int rr = 0; rr < 4; rr++) {
        int grow = q0 + wm * 16 + quad * 4 + rr;
        int gcol = h * 64 + t4 * 16 + ln;
        float v = Oacc[t4][rr] * a_self[rr]
                + Of[(wm * 16 + quad * 4 + rr) * 68 + t4 * 16 + ln];
        v /= l_[rr];
        og[(long)grow * 1024 + gcol] = f2b(v * gate[(long)grow * 1024 + gcol]);
      }
    }
  }
}

// ---------------------------------------------------------------------------
// ln2: hln = LN(sbuf) bf16; out = sbuf + b2 (pre-init for mlp2 atomics)
// ---------------------------------------------------------------------------
__global__ __launch_bounds__(256) void ln2(
    const float* __restrict__ sbuf, const float* __restrict__ g,
    const float* __restrict__ b, const float* __restrict__ b2,
    ushort_t* __restrict__ hln, float* __restrict__ out) {
  __shared__ float ps[8];
  int row = blockIdx.x, t = threadIdx.x;
  long base = (long)row * 1024 + t * 4;
  float4 v = *(const float4*)(sbuf + base);
  float4 b2v = *(const float4*)(b2 + t * 4);
  float4 ov; ov.x = v.x + b2v.x; ov.y = v.y + b2v.y; ov.z = v.z + b2v.z; ov.w = v.w + b2v.w;
  *(float4*)(out + base) = ov;
  float s  = v.x + v.y + v.z + v.w;
  float sq = v.x*v.x + v.y*v.y + v.z*v.z + v.w*v.w;
#pragma unroll
  for (int k = 1; k < 64; k <<= 1) { s += __shfl_xor(s, k); sq += __shfl_xor(sq, k); }
  if ((t & 63) == 0) { ps[t >> 6] = s; ps[4 + (t >> 6)] = sq; }
  __syncthreads();
  s  = ps[0] + ps[1] + ps[2] + ps[3];
  sq = ps[4] + ps[5] + ps[6] + ps[7];
  float mu = s * (1.f / 1024.f);
  float rsd = rsqrtf(sq * (1.f / 1024.f) - mu * mu + 1e-5f);
  float4 gv = *(const float4*)(g + t * 4);
  float4 bv = *(const float4*)(b + t * 4);
  uint2 o;
  o.x = pack2((v.x - mu) * rsd * gv.x + bv.x, (v.y - mu) * rsd * gv.y + bv.y);
  o.y = pack2((v.z - mu) * rsd * gv.z + bv.z, (v.w - mu) * rsd * gv.w + bv.w);
  *(uint2*)(hln + base) = o;
}

// ---------------------------------------------------------------------------
extern "C" void kernel_launch(void* const* d_in, const int* in_sizes, int n_in,
                              void* d_out, int out_size, void* d_ws, size_t ws_size,
                              hipStream_t stream) {
  const float* seq    = (const float*)d_in[0];
  const float* pw     = (const float*)d_in[1];
  const float* ln1_g  = (const float*)d_in[3];
  const float* ln1_b  = (const float*)d_in[4];
  const float* proj_w = (const float*)d_in[5];
  const float* g_w    = (const float*)d_in[6];
  const float* g_b    = (const float*)d_in[7];
  const float* o_w    = (const float*)d_in[8];
  const float* o_b    = (const float*)d_in[9];
  const float* p2s_g  = (const float*)d_in[10];
  const float* p2s_b  = (const float*)d_in[11];
  const float* p2s_w  = (const float*)d_in[12];
  const float* mlp_g  = (const float*)d_in[13];
  const float* mlp_bb = (const float*)d_in[14];
  const float* w1     = (const float*)d_in[15];
  const float* b1     = (const float*)d_in[16];
  const float* w2     = (const float*)d_in[17];
  const float* b2     = (const float*)d_in[18];
  float* out = (float*)d_out;
  char* ws = (char*)d_ws;

  ushort_t* biasH = (ushort_t*)(ws + OFF_BIASH);
  ushort_t* ybf   = (ushort_t*)(ws + OFF_Y);
  ushort_t* qs    = (ushort_t*)(ws + OFF_QS);
  ushort_t* ks    = (ushort_t*)(ws + OFF_KS);
  ushort_t* vt    = (ushort_t*)(ws + OFF_VT);
  float* gatebuf  = (float*)(ws + OFF_GATE);
  ushort_t* og    = (ushort_t*)(ws + OFF_OG);
  float* sbuf     = (float*)(ws + OFF_S);
  ushort_t* hln   = (ushort_t*)(ws + OFF_HLN);
  ushort_t* h1    = (ushort_t*)(ws + OFF_H1);
  ushort_t* wpg   = (ushort_t*)(ws + OFF_WPG);
  ushort_t* wo    = (ushort_t*)(ws + OFF_WO);
  ushort_t* w1t   = (ushort_t*)(ws + OFF_W1);
  ushort_t* w2t   = (ushort_t*)(ws + OFF_W2);

  // K1: p2s(MFMA, comb loads) + transposes + ln1 + sbuf init
  mega1<<<7936, 256, 0, stream>>>(pw, p2s_g, p2s_b, p2s_w,
                                  proj_w, g_w, o_w, w1, w2,
                                  seq, ln1_g, ln1_b, o_b,
                                  biasH, wpg, wo, w1t, w2t, ybf, sbuf);
  // K2: merged proj+gate GEMM -> qkv scatter + sigmoid gate (512 blocks)
  gemm64<6><<<dim3(64, 8, 1), 256, 0, stream>>>(ybf, wpg, 1024, 1024, 1024,
                                                g_b, nullptr, nullptr, 0,
                                                qs, ks, vt, gatebuf);
  // K3: flash attention (+bias, +gate) -> og bf16
  flash_attn<<<dim3(16, 16), 256, 0, stream>>>(qs, ks, vt, biasH, gatebuf, og);
  // K4: o_w split-K=4 atomicAdd into sbuf (512 blocks)
  gemm64<7><<<dim3(16, 8, 4), 256, 0, stream>>>(og, wo, 1024, 1024, 256,
                                                nullptr, sbuf, nullptr, 1024,
                                                nullptr, nullptr, nullptr, nullptr);
  // K5: hln = LN(s); out = s + b2
  ln2<<<512, 256, 0, stream>>>(sbuf, mlp_g, mlp_bb, b2, hln, out);
  // K6: h1 = relu(hln @ w1 + b1) bf16 (512 blocks)
  gemm64<3><<<dim3(64, 8, 1), 256, 0, stream>>>(hln, w1t, 1024, 1024, 1024,
                                                b1, nullptr, h1, 4096,
                                                nullptr, nullptr, nullptr, nullptr);
  // K7: mlp2 split-K=4 atomicAdd into out (512 blocks)
  gemm64<7><<<dim3(16, 8, 4), 256, 0, stream>>>(h1, w2t, 4096, 4096, 1024,
                                                nullptr, out, nullptr, 1024,
                                                nullptr, nullptr, nullptr, nullptr);
}

// Round 2
// 328.605 us; speedup vs baseline: 1.0128x; 1.0128x over previous
//
#include <hip/hip_runtime.h>

// ---------------------------------------------------------------------------
// SeqPairAttentionOutput on MI355X — round 7: 7 launches.
// r7: K4 split-K atomics -> per-z partial buffers, reduced in ln2
//     (s = seq + o_b + sum(partials)); K7 atomics staggered per z so
//     concurrent z-blocks hit disjoint output tiles; flash_attn gets
//     reg ping-pong prefetch of K/V/bias with raw barriers (counted lgkm,
//     vmcnt NOT drained) + coalesced bias staging through LDS.
// ---------------------------------------------------------------------------

typedef __attribute__((ext_vector_type(8))) short bfrag;   // 8 bf16 (4 VGPRs)
typedef __attribute__((ext_vector_type(4))) float f32x4;
typedef unsigned short ushort_t;
typedef unsigned int u32;

#define AS1 __attribute__((address_space(1)))
#define AS3 __attribute__((address_space(3)))

__device__ __forceinline__ void gll16(const void* g, void* l) {
  __builtin_amdgcn_global_load_lds((const AS1 u32*)g, (AS3 u32*)l, 16, 0, 0);
}

__device__ __forceinline__ unsigned short f2b(float x) {
  union { float f; unsigned u; } a; a.f = x;
  unsigned r = a.u + 0x7fffu + ((a.u >> 16) & 1u);   // RNE
  return (unsigned short)(r >> 16);
}
__device__ __forceinline__ unsigned pack2(float a, float b) {
  return (unsigned)f2b(a) | ((unsigned)f2b(b) << 16);
}
__device__ __forceinline__ float b2f(ushort_t u) {
  union { float f; unsigned v; } a; a.v = ((unsigned)u) << 16; return a.f;
}

// workspace layout (bytes)
#define OFF_BIASH ((size_t)0)                        // bias bf16 [16][512][512] 8MB
#define OFF_Y     ((size_t)8388608)                  // y bf16 [512][1024] 1MB
#define OFF_QS    (OFF_Y    + (size_t)1048576)
#define OFF_KS    (OFF_QS   + (size_t)1048576)
#define OFF_VT    (OFF_KS   + (size_t)1048576)       // v^T bf16 [16][64][512]
#define OFF_GATE  (OFF_VT   + (size_t)1048576)       // gate f32 [512][1024] 2MB
#define OFF_OG    (OFF_GATE + (size_t)2097152)       // gate*o bf16 1MB
#define OFF_S     (OFF_OG   + (size_t)1048576)       // (unused in r7) 2MB
#define OFF_HLN   (OFF_S    + (size_t)2097152)       // LN(s) bf16 1MB
#define OFF_H1    (OFF_HLN  + (size_t)1048576)       // h1 bf16 [512][4096] 4MB
#define OFF_WPG   (OFF_H1   + (size_t)4194304)       // [proj|g]^T bf16 [4096][1024] 8MB
#define OFF_WO    (OFF_WPG  + (size_t)8388608)       // o_w^T bf16 2MB
#define OFF_W1    (OFF_WO   + (size_t)2097152)       // w1^T bf16 8MB
#define OFF_W2    (OFF_W1   + (size_t)8388608)       // w2^T bf16 8MB
#define OFF_PART  (OFF_W2   + (size_t)8388608)       // K4 partials f32 [4][512][1024] 8MB

// ---------------------------------------------------------------------------
// transpose + cvt helper: W[K][N] -> Wt[N][K] bf16 (one 64x64 tile)
// ---------------------------------------------------------------------------
__device__ __forceinline__ void transp_tile(
    const float* __restrict__ W, ushort_t* __restrict__ Wt, int K, int N,
    int bx, int by, int tid, float* smem) {
  float (*tile)[65] = (float(*)[65])smem;
  int n0 = bx * 64, k0 = by * 64;
  int tr = tid >> 4, tc = (tid & 15) * 4;
#pragma unroll
  for (int i = 0; i < 4; i++) {
    int r = tr + i * 16;
    f32x4 v = __builtin_nontemporal_load(
        (const f32x4*)&W[(long)(k0 + r) * N + n0 + tc]);
    tile[r][tc] = v.x; tile[r][tc + 1] = v.y; tile[r][tc + 2] = v.z; tile[r][tc + 3] = v.w;
  }
  __syncthreads();
  int nr = tid >> 2, kk = (tid & 3) * 16;
  ushort_t* dst = Wt + (long)(n0 + nr) * K + k0 + kk;
  uint4 q;
  q.x = pack2(tile[kk + 0][nr], tile[kk + 1][nr]);
  q.y = pack2(tile[kk + 2][nr], tile[kk + 3][nr]);
  q.z = pack2(tile[kk + 4][nr], tile[kk + 5][nr]);
  q.w = pack2(tile[kk + 6][nr], tile[kk + 7][nr]);
  *(uint4*)dst = q;
  uint4 q2;
  q2.x = pack2(tile[kk + 8][nr],  tile[kk + 9][nr]);
  q2.y = pack2(tile[kk + 10][nr], tile[kk + 11][nr]);
  q2.z = pack2(tile[kk + 12][nr], tile[kk + 13][nr]);
  q2.w = pack2(tile[kk + 14][nr], tile[kk + 15][nr]);
  *(uint4*)(dst + 8) = q2;
}

// ---------------------------------------------------------------------------
// mega1: [0,4096) p2s MFMA | [4096,7424) transposes | [7424,7936) ln1
// ---------------------------------------------------------------------------
__global__ __launch_bounds__(256) void mega1(
    const float* __restrict__ pw,
    const float* __restrict__ p2s_g, const float* __restrict__ p2s_b,
    const float* __restrict__ p2s_w,
    const float* __restrict__ proj_w, const float* __restrict__ g_w,
    const float* __restrict__ o_w, const float* __restrict__ w1,
    const float* __restrict__ w2,
    const float* __restrict__ seq, const float* __restrict__ ln1_g,
    const float* __restrict__ ln1_b,
    ushort_t* __restrict__ biasH, ushort_t* __restrict__ wpg,
    ushort_t* __restrict__ wo, ushort_t* __restrict__ w1t,
    ushort_t* __restrict__ w2t, ushort_t* __restrict__ ybf) {
  __shared__ float smemF[5920];
  const int id = blockIdx.x, t = threadIdx.x;

  if (id < 4096) {
    // ---- p2s: 64 pairs/block, MFMA dot ----
    ushort_t* wb  = (ushort_t*)smemF;        // 2048
    ushort_t* zsb = wb + 2048;               // 64 x 136
    ushort_t* res = zsb + 64 * 136;          // 16 x 68
    const int w = t >> 6, lane = t & 63, ln = lane & 15, quad = lane >> 4;
    const long pair0 = (long)id * 64;
    const int p = w * 16 + (lane >> 2);      // local pair 0..63
    const int j = lane & 3;                  // quarter

    // stage w coalesced -> bf16 B-frag layout
#pragma unroll
    for (int i = t; i < 2048; i += 256) {
      int f = i >> 4, hh = i & 15;
      int chunk = f >> 5, q2 = (f >> 3) & 3, jj = f & 7;
      wb[(chunk * 64 + q2 * 16 + hh) * 8 + jj] = f2b(p2s_w[i]);
    }

    // x comb loads: lane j reads floats {j*4 + q*16 .. +4}, 64B line per 4 lanes
    const float* xbase = pw + (pair0 + p) * 128 + j * 4;
    f32x4 xv[8];
#pragma unroll
    for (int q = 0; q < 8; q++)
      xv[q] = __builtin_nontemporal_load((const f32x4*)(xbase + q * 16));
    float s = 0.f, sq = 0.f;
#pragma unroll
    for (int q = 0; q < 8; q++) {
      s  += xv[q].x + xv[q].y + xv[q].z + xv[q].w;
      sq += xv[q].x*xv[q].x + xv[q].y*xv[q].y + xv[q].z*xv[q].z + xv[q].w*xv[q].w;
    }
    s += __shfl_xor(s, 1); s += __shfl_xor(s, 2);
    sq += __shfl_xor(sq, 1); sq += __shfl_xor(sq, 2);
    float mu = s * (1.f / 128.f);
    float rs = rsqrtf(sq * (1.f / 128.f) - mu * mu + 1e-5f);

#pragma unroll
    for (int q = 0; q < 8; q++) {
      f32x4 gv = *(const f32x4*)(p2s_g + j * 4 + q * 16);
      f32x4 bv = *(const f32x4*)(p2s_b + j * 4 + q * 16);
      uint2 o;
      o.x = pack2((xv[q].x - mu) * rs * gv.x + bv.x, (xv[q].y - mu) * rs * gv.y + bv.y);
      o.y = pack2((xv[q].z - mu) * rs * gv.z + bv.z, (xv[q].w - mu) * rs * gv.w + bv.w);
      *(uint2*)&zsb[p * 136 + q * 16 + j * 4] = o;
    }
    __syncthreads();

    // wave w: pairs [w*16, w*16+16) x 16 heads, K=128 via 4 MFMA
    f32x4 acc = (f32x4){0.f, 0.f, 0.f, 0.f};
#pragma unroll
    for (int chunk = 0; chunk < 4; chunk++) {
      bfrag a  = *(const bfrag*)&zsb[(w * 16 + ln) * 136 + chunk * 32 + quad * 8];
      bfrag bf = *(const bfrag*)&wb[(chunk * 64 + quad * 16 + ln) * 8];
      acc = __builtin_amdgcn_mfma_f32_16x16x32_bf16(a, bf, acc, 0, 0, 0);
    }
    *(uint2*)&res[ln * 68 + w * 16 + quad * 4] =
        (uint2){pack2(acc[0], acc[1]), pack2(acc[2], acc[3])};
    __syncthreads();
    {
      int hh = t >> 4, base = (t & 15) * 4;
      *(uint2*)&biasH[(long)hh * 262144 + pair0 + base] =
          *(const uint2*)&res[hh * 68 + base];
    }
  } else if (id < 7424) {
    int j = id - 4096;
    if (j < 768)       transp_tile(proj_w, wpg, 1024, 3072, j % 48, j / 48, t, smemF);
    else if (j < 1024) { j -= 768;  transp_tile(g_w, wpg + (long)3072 * 1024, 1024, 1024, j % 16, j / 16, t, smemF); }
    else if (j < 1280) { j -= 1024; transp_tile(o_w, wo, 1024, 1024, j % 16, j / 16, t, smemF); }
    else if (j < 2304) { j -= 1280; transp_tile(w1, w1t, 1024, 4096, j % 64, j / 64, t, smemF); }
    else               { j -= 2304; transp_tile(w2, w2t, 4096, 1024, j % 16, j / 16, t, smemF); }
  } else {
    // ---- ln1 -> ybf ----
    int row = id - 7424;
    long base = (long)row * 1024 + t * 4;
    float4 v = *(const float4*)(seq + base);
    float s  = v.x + v.y + v.z + v.w;
    float sq = v.x*v.x + v.y*v.y + v.z*v.z + v.w*v.w;
#pragma unroll
    for (int k = 1; k < 64; k <<= 1) { s += __shfl_xor(s, k); sq += __shfl_xor(sq, k); }
    if ((t & 63) == 0) { smemF[t >> 6] = s; smemF[4 + (t >> 6)] = sq; }
    __syncthreads();
    s  = smemF[0] + smemF[1] + smemF[2] + smemF[3];
    sq = smemF[4] + smemF[5] + smemF[6] + smemF[7];
    float mu = s * (1.f / 1024.f);
    float rsd = rsqrtf(sq * (1.f / 1024.f) - mu * mu + 1e-5f);
    float4 gv = *(const float4*)(ln1_g + t * 4);
    float4 bv = *(const float4*)(ln1_b + t * 4);
    uint2 o;
    o.x = pack2((v.x - mu) * rsd * gv.x + bv.x, (v.y - mu) * rsd * gv.y + bv.y);
    o.y = pack2((v.z - mu) * rsd * gv.z + bv.z, (v.w - mu) * rsd * gv.w + bv.w);
    *(uint2*)(ybf + base) = o;
  }
}

// ---------------------------------------------------------------------------
// gemm64: 64x64 tile, depth-3 pipelined gll16 staging over 4 LDS buffers,
// counted s_waitcnt vmcnt, one raw s_barrier per K-iter.
// EPI 3: relu(acc+bias1)->bf16 | EPI 6: qkv/gate scatter
// EPI 7: atomicAdd f32 with per-z n-tile stagger (disjoint concurrent tiles)
// EPI 8: per-z partial write (no atomics)
// ---------------------------------------------------------------------------
template <int EPI>
__global__ __launch_bounds__(256) void gemm64(
    const ushort_t* __restrict__ A, const ushort_t* __restrict__ Bt,
    int lda, int ldb, int Ksplit,
    const float* __restrict__ bias1,
    float* __restrict__ outF, ushort_t* __restrict__ outH, int ldc,
    ushort_t* __restrict__ qs, ushort_t* __restrict__ ks,
    ushort_t* __restrict__ vt, float* __restrict__ gatebuf) {
  __shared__ ushort_t As[4][64 * 32];   // 4 KB each
  __shared__ ushort_t Bs[4][64 * 32];
  const int tid = threadIdx.x;
  const int w = tid >> 6, lane = tid & 63;
  const int ln = lane & 15, quad = lane >> 4;
  const int wm = w >> 1, wn = w & 1;
  const int z = blockIdx.z;
  // EPI7: stagger n-tile by z so concurrent z-blocks atomically add to
  // disjoint output tiles (gridDim.x == 16 for the split-K launches).
  const int nblk = (EPI == 7) ? ((blockIdx.x + z * 4) & 15) : blockIdx.x;
  const int m0 = blockIdx.y * 64, n0 = nblk * 64;
  const int Koff = (EPI >= 7) ? z * Ksplit : 0;

  const ushort_t* ga = A  + (long)(m0 + (tid >> 2)) * lda + Koff + (tid & 3) * 8;
  const ushort_t* gb = Bt + (long)(n0 + (tid >> 2)) * ldb + Koff + (tid & 3) * 8;
  unsigned wofs = __builtin_amdgcn_readfirstlane(w * 1024);
  char* lAw = (char*)&As[0][0] + wofs;
  char* lBw = (char*)&Bs[0][0] + wofs;

  f32x4 acc[2][2];
#pragma unroll
  for (int i = 0; i < 2; i++)
#pragma unroll
    for (int jj = 0; jj < 2; jj++) acc[i][jj] = (f32x4){0.f, 0.f, 0.f, 0.f};

  auto stage = [&](int t) {
    int boff = (t & 3) * 4096;
    gll16(ga + t * 32, lAw + boff);
    gll16(gb + t * 32, lBw + boff);
  };
  auto body = [&](int b) {
    const ushort_t* Ab = (const ushort_t*)((const char*)&As[0][0] + b * 4096);
    const ushort_t* Bb = (const ushort_t*)((const char*)&Bs[0][0] + b * 4096);
    bfrag a0 = *(const bfrag*)&Ab[(wm * 32 + ln) * 32 + quad * 8];
    bfrag a1 = *(const bfrag*)&Ab[(wm * 32 + 16 + ln) * 32 + quad * 8];
    bfrag b0 = *(const bfrag*)&Bb[(wn * 32 + ln) * 32 + quad * 8];
    bfrag b1 = *(const bfrag*)&Bb[(wn * 32 + 16 + ln) * 32 + quad * 8];
    acc[0][0] = __builtin_amdgcn_mfma_f32_16x16x32_bf16(a0, b0, acc[0][0], 0, 0, 0);
    acc[0][1] = __builtin_amdgcn_mfma_f32_16x16x32_bf16(a0, b1, acc[0][1], 0, 0, 0);
    acc[1][0] = __builtin_amdgcn_mfma_f32_16x16x32_bf16(a1, b0, acc[1][0], 0, 0, 0);
    acc[1][1] = __builtin_amdgcn_mfma_f32_16x16x32_bf16(a1, b1, acc[1][1], 0, 0, 0);
  };

  const int niter = Ksplit >> 5;
  stage(0);
  if (niter > 1) stage(1);
  if (niter > 2) stage(2);

  int k = 0;
  for (; k + 2 < niter; ++k) {            // steady state: tiles k+1,k+2 in flight
    asm volatile("s_waitcnt vmcnt(4)" ::: "memory");
    __builtin_amdgcn_s_barrier();
    __builtin_amdgcn_sched_barrier(0);
    if (k + 3 < niter) stage(k + 3);
    body(k & 3);
  }
  for (; k < niter; ++k) {                // tail: drain remaining tiles
    if (k + 1 < niter) { asm volatile("s_waitcnt vmcnt(2)" ::: "memory"); }
    else               { asm volatile("s_waitcnt vmcnt(0)" ::: "memory"); }
    __builtin_amdgcn_s_barrier();
    __builtin_amdgcn_sched_barrier(0);
    body(k & 3);
  }

#pragma unroll
  for (int am = 0; am < 2; am++) {
#pragma unroll
    for (int bn = 0; bn < 2; bn++) {
      int ocol = n0 + wn * 32 + bn * 16 + ln;
#pragma unroll
      for (int r = 0; r < 4; r++) {
        int orow = m0 + wm * 32 + am * 16 + quad * 4 + r;
        float v = acc[am][bn][r];
        if (EPI == 3) {
          v = fmaxf(v + bias1[ocol], 0.f);
          outH[(long)orow * ldc + ocol] = f2b(v);
        } else if (EPI == 6) {
          if (ocol < 3072) {
            int h = ocol / 192, jq = ocol - h * 192;
            if (jq < 64)       qs[((long)h * 512 + orow) * 64 + jq] = f2b(v * 0.125f);
            else if (jq < 128) ks[((long)h * 512 + orow) * 64 + (jq - 64)] = f2b(v);
            else               vt[((long)h * 64 + (jq - 128)) * 512 + orow] = f2b(v);
          } else {
            int gcol = ocol - 3072;
            float gv = v + bias1[gcol];
            gatebuf[(long)orow * 1024 + gcol] = 1.f / (1.f + __expf(-gv));
          }
        } else if (EPI == 7) {
          atomicAdd(&outF[(long)orow * ldc + ocol], v);
        } else { // EPI 8: per-z partial, no atomics
          outF[((long)z << 19) + (long)orow * 1024 + ocol] = v;
        }
      }
    }
  }
}

// ---------------------------------------------------------------------------
// flash attention: block = head x 32 q-rows, 4 waves (wm rows x wn key-half).
// r7: reg ping-pong prefetch of next tile's K/V/bias; raw s_barrier with
// counted lgkmcnt only (prefetch vmcnt stays in flight across barriers);
// bias staged coalesced through LDS (uint4) instead of scalar global reads.
// ---------------------------------------------------------------------------
__global__ __launch_bounds__(256) void flash_attn(
    const ushort_t* __restrict__ qs, const ushort_t* __restrict__ ks,
    const ushort_t* __restrict__ vt, const ushort_t* __restrict__ biasH,
    const float* __restrict__ gate, ushort_t* __restrict__ og) {
  __shared__ ushort_t Qs[32 * 72];
  __shared__ ushort_t Ks[64 * 72];
  __shared__ ushort_t Vs[64 * 72];
  __shared__ ushort_t Bb[32 * 72];
  __shared__ ushort_t Ps[4][16 * 40];
  const int tid = threadIdx.x;
  const int w = tid >> 6, lane = tid & 63, ln = lane & 15, quad = lane >> 4;
  const int wm = w >> 1, wn = w & 1;
  const int h = blockIdx.x, q0 = blockIdx.y * 32;

  { int r = tid >> 3, c = (tid & 7) * 8;
    *(uint4*)&Qs[r * 72 + c] = *(const uint4*)(qs + ((long)(h * 512 + q0 + r)) * 64 + c); }

  float m_[4], l_[4];
  f32x4 Oacc[4];
#pragma unroll
  for (int i = 0; i < 4; i++) { m_[i] = -1e30f; l_[i] = 0.f; Oacc[i] = (f32x4){0.f,0.f,0.f,0.f}; }

  const int rkv = tid >> 2, ckv = (tid & 3) * 16;
  const int rb = tid >> 3,  cb = (tid & 7) * 8;

  uint4 kA0, kA1, vA0, vA1, bA, kB0, kB1, vB0, vB1, bB;

  auto ldr = [&](int kt, uint4& K0, uint4& K1, uint4& V0, uint4& V1, uint4& BB) {
    const int k0 = kt * 64;
    const ushort_t* sk = ks + ((long)(h * 512 + k0 + rkv)) * 64 + ckv;
    K0 = *(const uint4*)sk;
    K1 = *(const uint4*)(sk + 8);
    const ushort_t* sv = vt + ((long)(h * 64 + rkv)) * 512 + k0 + ckv;
    V0 = *(const uint4*)sv;
    V1 = *(const uint4*)(sv + 8);
    BB = *(const uint4*)(biasH + ((long)(h * 512 + q0 + rb)) * 512 + k0 + cb);
  };

  auto tile = [&](int kt, uint4& K0, uint4& K1, uint4& V0, uint4& V1, uint4& BB,
                  uint4& nK0, uint4& nK1, uint4& nV0, uint4& nV1, uint4& nBB) {
    // barrier 1: prev tile's LDS reads done -> safe to overwrite K/V/Bb
    asm volatile("s_waitcnt lgkmcnt(0)" ::: "memory");
    __builtin_amdgcn_s_barrier();
    __builtin_amdgcn_sched_barrier(0);
    *(uint4*)&Ks[rkv * 72 + ckv]     = K0;
    *(uint4*)&Ks[rkv * 72 + ckv + 8] = K1;
    *(uint4*)&Vs[rkv * 72 + ckv]     = V0;
    *(uint4*)&Vs[rkv * 72 + ckv + 8] = V1;
    *(uint4*)&Bb[rb * 72 + cb]       = BB;
    if (kt < 7) ldr(kt + 1, nK0, nK1, nV0, nV1, nBB);  // overlaps compute below
    // barrier 2: staged LDS visible; prefetch vmcnt NOT drained
    asm volatile("s_waitcnt lgkmcnt(0)" ::: "memory");
    __builtin_amdgcn_s_barrier();
    __builtin_amdgcn_sched_barrier(0);

    f32x4 acc[2];
#pragma unroll
    for (int t4 = 0; t4 < 2; t4++)
#pragma unroll
      for (int rr = 0; rr < 4; rr++)
        acc[t4][rr] = b2f(Bb[(wm * 16 + quad * 4 + rr) * 72 + wn * 32 + t4 * 16 + ln]);

#pragma unroll
    for (int s = 0; s < 2; s++) {
      bfrag a = *(const bfrag*)&Qs[(wm * 16 + ln) * 72 + s * 32 + quad * 8];
#pragma unroll
      for (int t4 = 0; t4 < 2; t4++) {
        bfrag b = *(const bfrag*)&Ks[(wn * 32 + t4 * 16 + ln) * 72 + s * 32 + quad * 8];
        acc[t4] = __builtin_amdgcn_mfma_f32_16x16x32_bf16(a, b, acc[t4], 0, 0, 0);
      }
    }

    // wave-private online softmax over this wave's 32 keys
    float mt[4];
#pragma unroll
    for (int rr = 0; rr < 4; rr++) mt[rr] = fmaxf(acc[0][rr], acc[1][rr]);
#pragma unroll
    for (int xm = 1; xm < 16; xm <<= 1)
#pragma unroll
      for (int rr = 0; rr < 4; rr++) mt[rr] = fmaxf(mt[rr], __shfl_xor(mt[rr], xm));
    float al[4];
#pragma unroll
    for (int rr = 0; rr < 4; rr++) {
      float mn = fmaxf(m_[rr], mt[rr]);
      al[rr] = __expf(m_[rr] - mn);
      m_[rr] = mn;
    }
#pragma unroll
    for (int t4 = 0; t4 < 2; t4++)
#pragma unroll
      for (int rr = 0; rr < 4; rr++)
        acc[t4][rr] = __expf(acc[t4][rr] - m_[rr]);
    float rsl[4];
#pragma unroll
    for (int rr = 0; rr < 4; rr++) rsl[rr] = acc[0][rr] + acc[1][rr];
#pragma unroll
    for (int xm = 1; xm < 16; xm <<= 1)
#pragma unroll
      for (int rr = 0; rr < 4; rr++) rsl[rr] += __shfl_xor(rsl[rr], xm);
#pragma unroll
    for (int rr = 0; rr < 4; rr++) l_[rr] = l_[rr] * al[rr] + rsl[rr];
#pragma unroll
    for (int t4 = 0; t4 < 4; t4++)
#pragma unroll
      for (int rr = 0; rr < 4; rr++) Oacc[t4][rr] *= al[rr];

    // P -> wave-private LDS (C-layout -> A-layout round trip)
#pragma unroll
    for (int t4 = 0; t4 < 2; t4++)
#pragma unroll
      for (int rr = 0; rr < 4; rr++)
        Ps[w][(quad * 4 + rr) * 40 + t4 * 16 + ln] = f2b(acc[t4][rr]);
    __builtin_amdgcn_wave_barrier();
    __builtin_amdgcn_s_waitcnt(0xC07F);   // lgkmcnt(0), vm/exp unconstrained
    __builtin_amdgcn_wave_barrier();

    // O += P V (this wave's 32 keys)
    {
      bfrag a = *(const bfrag*)&Ps[w][ln * 40 + quad * 8];
#pragma unroll
      for (int t4 = 0; t4 < 4; t4++) {
        bfrag b = *(const bfrag*)&Vs[(t4 * 16 + ln) * 72 + wn * 32 + quad * 8];
        Oacc[t4] = __builtin_amdgcn_mfma_f32_16x16x32_bf16(a, b, Oacc[t4], 0, 0, 0);
      }
    }
  };

  ldr(0, kA0, kA1, vA0, vA1, bA);
#pragma unroll
  for (int kt2 = 0; kt2 < 8; kt2 += 2) {
    tile(kt2,     kA0, kA1, vA0, vA1, bA, kB0, kB1, vB0, vB1, bB);
    tile(kt2 + 1, kB0, kB1, vB0, vB1, bB, kA0, kA1, vA0, vA1, bA);
  }

  // merge the two wn key-half streams (flash-decoding style)
  __syncthreads();
  float* ml = (float*)(void*)Ks;    // [4 waves][16 rows][2]
  if (ln == 0)
#pragma unroll
    for (int rr = 0; rr < 4; rr++) {
      ml[(w * 16 + quad * 4 + rr) * 2 + 0] = m_[rr];
      ml[(w * 16 + quad * 4 + rr) * 2 + 1] = l_[rr];
    }
  __syncthreads();
  const int pw_ = wm * 2 + (wn ^ 1);
  float a_self[4];
#pragma unroll
  for (int rr = 0; rr < 4; rr++) {
    float mo = ml[(pw_ * 16 + quad * 4 + rr) * 2 + 0];
    float lo = ml[(pw_ * 16 + quad * 4 + rr) * 2 + 1];
    float mF = fmaxf(m_[rr], mo);
    a_self[rr] = __expf(m_[rr] - mF);
    l_[rr] = l_[rr] * a_self[rr] + lo * __expf(mo - mF);   // final l
  }
  float* Of = (float*)(void*)Vs;    // [2 wm][16 rows][68]
  if (wn == 1) {
#pragma unroll
    for (int t4 = 0; t4 < 4; t4++)
#pragma unroll
      for (int rr = 0; rr < 4; rr++)
        Of[(wm * 16 + quad * 4 + rr) * 68 + t4 * 16 + ln] = Oacc[t4][rr] * a_self[rr];
  }
  __syncthreads();
  if (wn == 0) {
#pragma unroll
    for (int t4 = 0; t4 < 4; t4++) {
#pragma unroll
      for (int rr = 0; rr < 4; rr++) {
        int grow = q0 + wm * 16 + quad * 4 + rr;
        int gcol = h * 64 + t4 * 16 + ln;
        float v = Oacc[t4][rr] * a_self[rr]
                + Of[(wm * 16 + quad * 4 + rr) * 68 + t4 * 16 + ln];
        v /= l_[rr];
        og[(long)grow * 1024 + gcol] = f2b(v * gate[(long)grow * 1024 + gcol]);
      }
    }
  }
}

// ---------------------------------------------------------------------------
// ln2: s = seq + o_b + sum_z part[z]; hln = LN(s) bf16; out = s + b2
// ---------------------------------------------------------------------------
__global__ __launch_bounds__(256) void ln2(
    const float* __restrict__ seq, const float* __restrict__ part,
    const float* __restrict__ o_b, const float* __restrict__ g,
    const float* __restrict__ b, const float* __restrict__ b2,
    ushort_t* __restrict__ hln, float* __restrict__ out) {
  __shared__ float ps[8];
  int row = blockIdx.x, t = threadIdx.x;
  long base = (long)row * 1024 + t * 4;
  float4 v = *(const float4*)(seq + base);
  float4 ob = *(const float4*)(o_b + t * 4);
  v.x += ob.x; v.y += ob.y; v.z += ob.z; v.w += ob.w;
#pragma unroll
  for (int z = 0; z < 4; z++) {
    float4 pv = *(const float4*)(part + ((long)z << 19) + base);
    v.x += pv.x; v.y += pv.y; v.z += pv.z; v.w += pv.w;
  }
  float4 b2v = *(const float4*)(b2 + t * 4);
  float4 ov; ov.x = v.x + b2v.x; ov.y = v.y + b2v.y; ov.z = v.z + b2v.z; ov.w = v.w + b2v.w;
  *(float4*)(out + base) = ov;
  float s  = v.x + v.y + v.z + v.w;
  float sq = v.x*v.x + v.y*v.y + v.z*v.z + v.w*v.w;
#pragma unroll
  for (int k = 1; k < 64; k <<= 1) { s += __shfl_xor(s, k); sq += __shfl_xor(sq, k); }
  if ((t & 63) == 0) { ps[t >> 6] = s; ps[4 + (t >> 6)] = sq; }
  __syncthreads();
  s  = ps[0] + ps[1] + ps[2] + ps[3];
  sq = ps[4] + ps[5] + ps[6] + ps[7];
  float mu = s * (1.f / 1024.f);
  float rsd = rsqrtf(sq * (1.f / 1024.f) - mu * mu + 1e-5f);
  float4 gv = *(const float4*)(g + t * 4);
  float4 bv = *(const float4*)(b + t * 4);
  uint2 o;
  o.x = pack2((v.x - mu) * rsd * gv.x + bv.x, (v.y - mu) * rsd * gv.y + bv.y);
  o.y = pack2((v.z - mu) * rsd * gv.z + bv.z, (v.w - mu) * rsd * gv.w + bv.w);
  *(uint2*)(hln + base) = o;
}

// ---------------------------------------------------------------------------
extern "C" void kernel_launch(void* const* d_in, const int* in_sizes, int n_in,
                              void* d_out, int out_size, void* d_ws, size_t ws_size,
                              hipStream_t stream) {
  const float* seq    = (const float*)d_in[0];
  const float* pw     = (const float*)d_in[1];
  const float* ln1_g  = (const float*)d_in[3];
  const float* ln1_b  = (const float*)d_in[4];
  const float* proj_w = (const float*)d_in[5];
  const float* g_w    = (const float*)d_in[6];
  const float* g_b    = (const float*)d_in[7];
  const float* o_w    = (const float*)d_in[8];
  const float* o_b    = (const float*)d_in[9];
  const float* p2s_g  = (const float*)d_in[10];
  const float* p2s_b  = (const float*)d_in[11];
  const float* p2s_w  = (const float*)d_in[12];
  const float* mlp_g  = (const float*)d_in[13];
  const float* mlp_bb = (const float*)d_in[14];
  const float* w1     = (const float*)d_in[15];
  const float* b1     = (const float*)d_in[16];
  const float* w2     = (const float*)d_in[17];
  const float* b2     = (const float*)d_in[18];
  float* out = (float*)d_out;
  char* ws = (char*)d_ws;

  ushort_t* biasH = (ushort_t*)(ws + OFF_BIASH);
  ushort_t* ybf   = (ushort_t*)(ws + OFF_Y);
  ushort_t* qs    = (ushort_t*)(ws + OFF_QS);
  ushort_t* ks    = (ushort_t*)(ws + OFF_KS);
  ushort_t* vt    = (ushort_t*)(ws + OFF_VT);
  float* gatebuf  = (float*)(ws + OFF_GATE);
  ushort_t* og    = (ushort_t*)(ws + OFF_OG);
  ushort_t* hln   = (ushort_t*)(ws + OFF_HLN);
  ushort_t* h1    = (ushort_t*)(ws + OFF_H1);
  ushort_t* wpg   = (ushort_t*)(ws + OFF_WPG);
  ushort_t* wo    = (ushort_t*)(ws + OFF_WO);
  ushort_t* w1t   = (ushort_t*)(ws + OFF_W1);
  ushort_t* w2t   = (ushort_t*)(ws + OFF_W2);
  float* part4    = (float*)(ws + OFF_PART);

  // K1: p2s(MFMA, comb loads) + transposes + ln1
  mega1<<<7936, 256, 0, stream>>>(pw, p2s_g, p2s_b, p2s_w,
                                  proj_w, g_w, o_w, w1, w2,
                                  seq, ln1_g, ln1_b,
                                  biasH, wpg, wo, w1t, w2t, ybf);
  // K2: merged proj+gate GEMM -> qkv scatter + sigmoid gate (512 blocks)
  gemm64<6><<<dim3(64, 8, 1), 256, 0, stream>>>(ybf, wpg, 1024, 1024, 1024,
                                                g_b, nullptr, nullptr, 0,
                                                qs, ks, vt, gatebuf);
  // K3: flash attention (+bias, +gate) -> og bf16
  flash_attn<<<dim3(16, 16), 256, 0, stream>>>(qs, ks, vt, biasH, gatebuf, og);
  // K4: o_w split-K=4 -> per-z partials (no atomics)
  gemm64<8><<<dim3(16, 8, 4), 256, 0, stream>>>(og, wo, 1024, 1024, 256,
                                                nullptr, part4, nullptr, 1024,
                                                nullptr, nullptr, nullptr, nullptr);
  // K5: s = seq + o_b + sum(partials); hln = LN(s); out = s + b2
  ln2<<<512, 256, 0, stream>>>(seq, part4, o_b, mlp_g, mlp_bb, b2, hln, out);
  // K6: h1 = relu(hln @ w1 + b1) bf16 (512 blocks)
  gemm64<3><<<dim3(64, 8, 1), 256, 0, stream>>>(hln, w1t, 1024, 1024, 1024,
                                                b1, nullptr, h1, 4096,
                                                nullptr, nullptr, nullptr, nullptr);
  // K7: mlp2 split-K=4 atomicAdd into out, z-staggered n-tiles (512 blocks)
  gemm64<7><<<dim3(16, 8, 4), 256, 0, stream>>>(h1, w2t, 4096, 4096, 1024,
                                                nullptr, out, nullptr, 1024,
                                                nullptr, nullptr, nullptr, nullptr);
}